// Round 7
// baseline (948.020 us; speedup 1.0000x reference)
//
#include <hip/hip_runtime.h>
#include <hip/hip_bf16.h>
#include <math.h>

typedef __attribute__((ext_vector_type(8))) short bf16x8;
typedef __attribute__((ext_vector_type(4))) float f32x4;
typedef unsigned short ushort_t;

constexpr float F_CUTOFF = 10.0f;
constexpr float F_EPS_W  = 1e-5f;
constexpr float F_EPS_LN = 1e-5f;
constexpr float F_PI     = 3.14159265358979323846f;

__device__ __forceinline__ float silu_f(float v)   { return v / (1.0f + __expf(-v)); }
__device__ __forceinline__ float sigmoid_f(float v){ return 1.0f / (1.0f + __expf(-v)); }

__device__ __forceinline__ ushort_t f2bf(float f) {
    union { __hip_bfloat16 h; ushort_t u; } v; v.h = __float2bfloat16(f); return v.u;
}
__device__ __forceinline__ float bf2f(ushort_t u) {
    union { unsigned u; float f; } v; v.u = ((unsigned)u) << 16; return v.f;
}

__device__ __forceinline__ float f4c(const float4& v, int q) {
    return q == 0 ? v.x : q == 1 ? v.y : q == 2 ? v.z : v.w;
}

// ---------------------------------------------------------------------------
// CSR build
// ---------------------------------------------------------------------------
__global__ void count_kernel(const int* __restrict__ eidx, int* __restrict__ cnt, int E)
{
    int e = blockIdx.x * 256 + threadIdx.x;
    if (e < E) atomicAdd(&cnt[eidx[e]], 1);
}

__global__ __launch_bounds__(1024)
void scan_kernel(int* __restrict__ cnt /* in: counts, out: cursor */,
                 int* __restrict__ start, int N)
{
    __shared__ int part[1024];
    const int tid = threadIdx.x;
    const int C = (N + 1023) >> 10;
    const int base = tid * C;
    int s = 0;
    for (int i = 0; i < C; ++i) {
        int idx = base + i;
        if (idx < N) s += cnt[idx];
    }
    part[tid] = s;
    __syncthreads();
    for (int off = 1; off < 1024; off <<= 1) {
        int v = (tid >= off) ? part[tid - off] : 0;
        __syncthreads();
        part[tid] += v;
        __syncthreads();
    }
    int run = part[tid] - s;   // exclusive prefix
    for (int i = 0; i < C; ++i) {
        int idx = base + i;
        if (idx < N) {
            int c = cnt[idx];
            start[idx] = run;
            cnt[idx]   = run;   // cursor
            run += c;
        }
    }
    if (tid == 1023) start[N] = part[1023];
}

__global__ void scatter_kernel(const int* __restrict__ eidx, const float* __restrict__ dist,
                               int* __restrict__ cursor,
                               int* __restrict__ colp, int* __restrict__ nodep,
                               float* __restrict__ distp, int E)
{
    int e = blockIdx.x * 256 + threadIdx.x;
    if (e < E) {
        int row = eidx[e];
        int s = atomicAdd(&cursor[row], 1);
        colp[s]  = eidx[E + e];
        nodep[s] = row;
        distp[s] = dist[e];
    }
}

// ---------------------------------------------------------------------------
// Weight convert+transpose: fp32 [K][N] -> bf16 [N][K].
// ---------------------------------------------------------------------------
__global__ void cvt_transpose_kernel(const float* __restrict__ in, ushort_t* __restrict__ out,
                                     int K, int N, int logK)
{
    int idx = blockIdx.x * 256 + threadIdx.x;
    if (idx >= K * N) return;
    int n = idx >> logK;
    int k = idx & (K - 1);
    out[idx] = f2bf(in[k * N + n]);
}

// wcomb[c][j] = sum_n rbf_w2[j][n] * filt_w1[n][c]  -> bf16 [256][64]
__global__ void combine_w_kernel(const float* __restrict__ w2, const float* __restrict__ fw1,
                                 ushort_t* __restrict__ out)
{
    int idx = blockIdx.x * 256 + threadIdx.x;
    int c = idx >> 6, j = idx & 63;
    float s = 0.f;
    #pragma unroll 8
    for (int n = 0; n < 64; ++n) s += w2[j * 64 + n] * fw1[n * 256 + c];
    out[idx] = f2bf(s);
}

__global__ void combine_b_kernel(const float* __restrict__ b2, const float* __restrict__ fw1,
                                 const float* __restrict__ fb1, float* __restrict__ out)
{
    int c = threadIdx.x;
    float s = fb1[c];
    #pragma unroll 8
    for (int n = 0; n < 64; ++n) s += b2[n] * fw1[n * 256 + c];
    out[c] = s;
}

// ---------------------------------------------------------------------------
// y = x @ node_w + node_b, output bf16.
// ---------------------------------------------------------------------------
__global__ __launch_bounds__(256)
void gemm256_bf16_kernel(const float* __restrict__ A, const float* __restrict__ Wm,
                         const float* __restrict__ bias, ushort_t* __restrict__ out, int M)
{
    __shared__ float4 As4[64][64];
    const int t = threadIdx.x;
    const int row0 = blockIdx.x * 64;

    #pragma unroll
    for (int i = 0; i < 16; ++i) {
        int flat = t + i * 256;
        int r = flat >> 6, k4 = flat & 63;
        int row = row0 + r;
        float4 v = make_float4(0.f, 0.f, 0.f, 0.f);
        if (row < M) v = reinterpret_cast<const float4*>(A)[row * 64 + k4];
        As4[r][k4] = v;
    }
    __syncthreads();

    const int jt  = t & 31;
    const int et  = t >> 5;
    const int j04 = jt * 2;
    const int r0  = et * 8;

    float acc[8][8];
    #pragma unroll
    for (int r = 0; r < 8; ++r)
        #pragma unroll
        for (int c = 0; c < 8; ++c) acc[r][c] = 0.f;

    for (int k4 = 0; k4 < 64; ++k4) {
        float4 a4[8];
        #pragma unroll
        for (int r = 0; r < 8; ++r) a4[r] = As4[r0 + r][k4];
        #pragma unroll
        for (int q = 0; q < 4; ++q) {
            const int k = k4 * 4 + q;
            float4 b0 = reinterpret_cast<const float4*>(Wm)[k * 64 + j04];
            float4 b1 = reinterpret_cast<const float4*>(Wm)[k * 64 + j04 + 1];
            float bb[8] = {b0.x, b0.y, b0.z, b0.w, b1.x, b1.y, b1.z, b1.w};
            #pragma unroll
            for (int r = 0; r < 8; ++r) {
                float av = f4c(a4[r], q);
                #pragma unroll
                for (int c = 0; c < 8; ++c) acc[r][c] = fmaf(av, bb[c], acc[r][c]);
            }
        }
    }

    float4 bv0 = reinterpret_cast<const float4*>(bias)[j04];
    float4 bv1 = reinterpret_cast<const float4*>(bias)[j04 + 1];
    float bb[8] = {bv0.x, bv0.y, bv0.z, bv0.w, bv1.x, bv1.y, bv1.z, bv1.w};

    #pragma unroll
    for (int r = 0; r < 8; ++r) {
        int row = row0 + r0 + r;
        if (row >= M) continue;
        ushort_t o8[8];
        #pragma unroll
        for (int c = 0; c < 8; ++c) o8[c] = f2bf(acc[r][c] + bb[c]);
        *reinterpret_cast<uint4*>(out + (size_t)row * 256 + jt * 8) = *reinterpret_cast<uint4*>(o8);
    }
}

// ---------------------------------------------------------------------------
// Gate GEMM (fp32): out = A * sigmoid(A@W + b), in-place safe per 64-row block.
// ---------------------------------------------------------------------------
__global__ __launch_bounds__(256)
void gate_gemm_kernel(const float* __restrict__ A, const float* __restrict__ Wm,
                      const float* __restrict__ bias, float* __restrict__ out, int M)
{
    __shared__ float4 As4[64][64];
    const int t = threadIdx.x;
    const int row0 = blockIdx.x * 64;

    #pragma unroll
    for (int i = 0; i < 16; ++i) {
        int flat = t + i * 256;
        int r = flat >> 6, k4 = flat & 63;
        int row = row0 + r;
        float4 v = make_float4(0.f, 0.f, 0.f, 0.f);
        if (row < M) v = reinterpret_cast<const float4*>(A)[row * 64 + k4];
        As4[r][k4] = v;
    }
    __syncthreads();

    const int jt  = t & 31;
    const int et  = t >> 5;
    const int j04 = jt * 2;
    const int r0  = et * 8;

    float acc[8][8];
    #pragma unroll
    for (int r = 0; r < 8; ++r)
        #pragma unroll
        for (int c = 0; c < 8; ++c) acc[r][c] = 0.f;

    for (int k4 = 0; k4 < 64; ++k4) {
        float4 a4[8];
        #pragma unroll
        for (int r = 0; r < 8; ++r) a4[r] = As4[r0 + r][k4];
        #pragma unroll
        for (int q = 0; q < 4; ++q) {
            const int k = k4 * 4 + q;
            float4 b0 = reinterpret_cast<const float4*>(Wm)[k * 64 + j04];
            float4 b1 = reinterpret_cast<const float4*>(Wm)[k * 64 + j04 + 1];
            float bb[8] = {b0.x, b0.y, b0.z, b0.w, b1.x, b1.y, b1.z, b1.w};
            #pragma unroll
            for (int r = 0; r < 8; ++r) {
                float av = f4c(a4[r], q);
                #pragma unroll
                for (int c = 0; c < 8; ++c) acc[r][c] = fmaf(av, bb[c], acc[r][c]);
            }
        }
    }

    float4 bv0 = reinterpret_cast<const float4*>(bias)[j04];
    float4 bv1 = reinterpret_cast<const float4*>(bias)[j04 + 1];
    float bb[8] = {bv0.x, bv0.y, bv0.z, bv0.w, bv1.x, bv1.y, bv1.z, bv1.w};

    #pragma unroll
    for (int r = 0; r < 8; ++r) {
        int row = row0 + r0 + r;
        if (row >= M) continue;
        float4 a0 = As4[r0 + r][j04];
        float4 a1 = As4[r0 + r][j04 + 1];
        float aa[8] = {a0.x, a0.y, a0.z, a0.w, a1.x, a1.y, a1.z, a1.w};
        float o[8];
        #pragma unroll
        for (int c = 0; c < 8; ++c) o[c] = aa[c] * sigmoid_f(acc[r][c] + bb[c]);
        reinterpret_cast<float4*>(out)[row * 64 + j04]     = make_float4(o[0], o[1], o[2], o[3]);
        reinterpret_cast<float4*>(out)[row * 64 + j04 + 1] = make_float4(o[4], o[5], o[6], o[7]);
    }
}

// ---------------------------------------------------------------------------
// mlp_stage (proven): 32 rows, 4 waves (1m x 4n), LDS 512B-row swizzled.
// ---------------------------------------------------------------------------
template<int KS, int NT, bool SILU>
__device__ __forceinline__ void mlp_stage(const unsigned char* in, unsigned char* out,
                                          const ushort_t* __restrict__ Wt,
                                          const float* __restrict__ bias,
                                          int wn, int g, int q)
{
    constexpr int K = KS * 32;
    f32x4 acc[2][NT];
    #pragma unroll
    for (int mt = 0; mt < 2; ++mt)
        #pragma unroll
        for (int nt = 0; nt < NT; ++nt) acc[mt][nt] = (f32x4){0.f, 0.f, 0.f, 0.f};

    #pragma unroll
    for (int kk = 0; kk < KS; ++kk) {
        bf16x8 b[NT];
        #pragma unroll
        for (int nt = 0; nt < NT; ++nt) {
            int n = (wn * NT + nt) * 16 + q;
            b[nt] = *reinterpret_cast<const bf16x8*>(Wt + n * K + kk * 32 + g * 8);
        }
        bf16x8 a[2];
        #pragma unroll
        for (int mt = 0; mt < 2; ++mt) {
            int m = mt * 16 + q;
            int unit = (4 * kk + g) ^ (m & 7);
            a[mt] = *reinterpret_cast<const bf16x8*>(in + m * 512 + unit * 16);
        }
        #pragma unroll
        for (int mt = 0; mt < 2; ++mt)
            #pragma unroll
            for (int nt = 0; nt < NT; ++nt)
                acc[mt][nt] = __builtin_amdgcn_mfma_f32_16x16x32_bf16(a[mt], b[nt], acc[mt][nt], 0, 0, 0);
    }

    const bool evenq = (q & 1) == 0;
    #pragma unroll
    for (int nt = 0; nt < NT; ++nt) {
        int n0  = (wn * NT + nt) * 16 + q;
        int n_e = n0 & ~1;
        float2 bv = *reinterpret_cast<const float2*>(bias + n_e);
        #pragma unroll
        for (int mt = 0; mt < 2; ++mt) {
            float v[4], p[4];
            #pragma unroll
            for (int r = 0; r < 4; ++r) { v[r] = acc[mt][nt][r]; p[r] = __shfl_xor(v[r], 1, 64); }
            #pragma unroll
            for (int rr = 0; rr < 2; ++rr) {
                int r = evenq ? rr : (2 + rr);
                float lo = (evenq ? v[r] : p[r]) + bv.x;
                float hi = (evenq ? p[r] : v[r]) + bv.y;
                if (SILU) { lo = silu_f(lo); hi = silu_f(hi); }
                int m = mt * 16 + 4 * g + r;
                unsigned u = (unsigned)f2bf(lo) | ((unsigned)f2bf(hi) << 16);
                int byte = m * 512 + (((n_e >> 3) ^ (m & 7)) << 4) + ((n_e & 7) * 2);
                *reinterpret_cast<unsigned*>(out + byte) = u;
            }
        }
    }
}

// ---------------------------------------------------------------------------
// CSR edge kernel: 32 slot-ordered edges/block. Final stage writes msg to a
// 32 KB LDS overlay, then a column reduce stores per-node sums: interior
// nodes -> plain store, boundary nodes -> one atomic partial per column.
// ---------------------------------------------------------------------------
__global__ __launch_bounds__(256, 4)
void edge_csr_kernel(const float* __restrict__ distp, const int* __restrict__ colp,
                     const int* __restrict__ nodep, const int* __restrict__ start,
                     const float* __restrict__ centers, const float* __restrict__ widths,
                     const ushort_t* __restrict__ wt_rbf1, const float* __restrict__ rbf_b1,
                     const ushort_t* __restrict__ wt_comb, const float* __restrict__ b_comb,
                     const ushort_t* __restrict__ wt_f2, const float* __restrict__ filt_b2,
                     const ushort_t* __restrict__ wt_f3, const float* __restrict__ filt_b3,
                     const ushort_t* __restrict__ y, float* __restrict__ agg, int E)
{
    __shared__ __align__(16) unsigned char buf[32768];
    __shared__ int node_s[32];
    __shared__ int flag_s[32];
    unsigned char* bufA = buf;
    unsigned char* bufB = buf + 16384;

    const int t  = threadIdx.x;
    const int e0 = blockIdx.x * 32;
    const int wn   = t >> 6;
    const int lane = t & 63;
    const int g = lane >> 4, q = lane & 15;

    if (t < 32) {
        int ge = e0 + t;
        int nd = (ge < E) ? nodep[ge] : -1;
        node_s[t] = nd;
        int fl = 0;
        if (nd >= 0) {
            int lo = start[nd], hi = start[nd + 1];
            fl = (lo >= e0 && hi <= e0 + 32) ? 1 : 0;
        }
        flag_s[t] = fl;
    }

    // y prefetch (permuted col)
    const int e_own  = t >> 3;
    const int chunk  = t & 7;
    const int ge_own = e0 + e_own;
    const int col_own = (ge_own < E) ? colp[ge_own] : 0;
    uint4 yv[4];
    #pragma unroll
    for (int i = 0; i < 4; ++i)
        yv[i] = *reinterpret_cast<const uint4*>(y + (size_t)col_own * 256 + (i * 8 + chunk) * 8);

    // S0: RBF features r[32][64] -> bufA (swizzled)
    {
        float d = (ge_own < E) ? distp[ge_own] : F_CUTOFF;
        float env = (d < F_CUTOFF) ? 0.5f * (__cosf(d * (F_PI / F_CUTOFF)) + 1.0f) : 0.0f;
        unsigned char* rowp = bufA + e_own * 512;
        int k0 = chunk * 8;
        #pragma unroll
        for (int i = 0; i < 4; ++i) {
            int n = k0 + 2 * i;
            float c0 = centers[n],     w0 = fabsf(widths[n]) + F_EPS_W;
            float c1 = centers[n + 1], w1 = fabsf(widths[n + 1]) + F_EPS_W;
            float z0 = (d - c0) / w0, z1 = (d - c1) / w1;
            float r0 = env * __expf(-0.5f * z0 * z0);
            float r1 = env * __expf(-0.5f * z1 * z1);
            unsigned u = (unsigned)f2bf(r0) | ((unsigned)f2bf(r1) << 16);
            int byte = (((n >> 3) ^ (e_own & 7)) << 4) + ((n & 7) * 2);
            *reinterpret_cast<unsigned*>(rowp + byte) = u;
        }
    }
    __syncthreads();

    mlp_stage<2, 1, true>(bufA, bufB, wt_rbf1, rbf_b1, wn, g, q);  // t1
    __syncthreads();
    mlp_stage<2, 4, true>(bufB, bufA, wt_comb, b_comb, wn, g, q);  // f1
    __syncthreads();
    mlp_stage<8, 4, true>(bufA, bufB, wt_f2, filt_b2, wn, g, q);   // f2
    __syncthreads();   // bufA (f1) dead -> park y

    #pragma unroll
    for (int i = 0; i < 4; ++i)
        *reinterpret_cast<uint4*>(bufA + e_own * 512 + (i * 8 + chunk) * 16) = yv[i];
    __syncthreads();

    // final: Wf = f2@fw3+fb3; msg = y_lds * Wf (held in regs)
    f32x4 acc[2][4];
    #pragma unroll
    for (int mt = 0; mt < 2; ++mt)
        #pragma unroll
        for (int nt = 0; nt < 4; ++nt) acc[mt][nt] = (f32x4){0.f, 0.f, 0.f, 0.f};

    #pragma unroll
    for (int kk = 0; kk < 8; ++kk) {
        bf16x8 b[4];
        #pragma unroll
        for (int nt = 0; nt < 4; ++nt) {
            int n = (wn * 4 + nt) * 16 + q;
            b[nt] = *reinterpret_cast<const bf16x8*>(wt_f3 + n * 256 + kk * 32 + g * 8);
        }
        bf16x8 a[2];
        #pragma unroll
        for (int mt = 0; mt < 2; ++mt) {
            int m = mt * 16 + q;
            int unit = (4 * kk + g) ^ (m & 7);
            a[mt] = *reinterpret_cast<const bf16x8*>(bufB + m * 512 + unit * 16);
        }
        #pragma unroll
        for (int mt = 0; mt < 2; ++mt)
            #pragma unroll
            for (int nt = 0; nt < 4; ++nt)
                acc[mt][nt] = __builtin_amdgcn_mfma_f32_16x16x32_bf16(a[mt], b[nt], acc[mt][nt], 0, 0, 0);
    }

    float bn[4];
    int   nn[4];
    #pragma unroll
    for (int nt = 0; nt < 4; ++nt) { nn[nt] = (wn * 4 + nt) * 16 + q; bn[nt] = filt_b3[nn[nt]]; }

    // apply bias + y into acc (reads y from bufA)
    #pragma unroll
    for (int mt = 0; mt < 2; ++mt) {
        #pragma unroll
        for (int r = 0; r < 4; ++r) {
            int m = mt * 16 + 4 * g + r;
            const unsigned char* yrow = bufA + m * 512;
            #pragma unroll
            for (int nt = 0; nt < 4; ++nt) {
                float yvv = bf2f(*reinterpret_cast<const ushort_t*>(yrow + nn[nt] * 2));
                acc[mt][nt][r] = (acc[mt][nt][r] + bn[nt]) * yvv;
            }
        }
    }
    __syncthreads();   // all reads of bufA/bufB done -> overlay msg f32 [32][256]

    float* msgf = reinterpret_cast<float*>(buf);
    #pragma unroll
    for (int mt = 0; mt < 2; ++mt) {
        #pragma unroll
        for (int r = 0; r < 4; ++r) {
            int m  = mt * 16 + 4 * g + r;
            #pragma unroll
            for (int nt = 0; nt < 4; ++nt)
                msgf[m * 256 + nn[nt]] = acc[mt][nt][r];
        }
    }
    __syncthreads();

    // column reduce: thread t owns column j = t
    {
        const int j = t;
        float accv = 0.f;
        int cur = -2, rs = 0;
        #pragma unroll 4
        for (int r = 0; r < 32; ++r) {
            int nd = node_s[r];
            if (nd != cur) {
                if (cur >= 0) {
                    if (flag_s[rs]) agg[(size_t)cur * 256 + j] = accv;
                    else            unsafeAtomicAdd(&agg[(size_t)cur * 256 + j], accv);
                }
                cur = nd; rs = r; accv = msgf[r * 256 + j];
            } else {
                accv += msgf[r * 256 + j];
            }
        }
        if (cur >= 0) {
            if (flag_s[rs]) agg[(size_t)cur * 256 + j] = accv;
            else            unsafeAtomicAdd(&agg[(size_t)cur * 256 + j], accv);
        }
    }
}

// ---------------------------------------------------------------------------
// Fallback (ws too small): fused atomic-scatter edge kernel (R4 proven).
// ---------------------------------------------------------------------------
__global__ __launch_bounds__(256, 4)
void edge_atomic_kernel(const float* __restrict__ dist, const int* __restrict__ eidx,
                        const float* __restrict__ centers, const float* __restrict__ widths,
                        const ushort_t* __restrict__ wt_rbf1, const float* __restrict__ rbf_b1,
                        const ushort_t* __restrict__ wt_comb, const float* __restrict__ b_comb,
                        const ushort_t* __restrict__ wt_f2, const float* __restrict__ filt_b2,
                        const ushort_t* __restrict__ wt_f3, const float* __restrict__ filt_b3,
                        const ushort_t* __restrict__ y, float* __restrict__ agg, int E)
{
    __shared__ __align__(16) unsigned char bufA[16384];
    __shared__ __align__(16) unsigned char bufB[16384];
    __shared__ int rs_s[32];

    const int t  = threadIdx.x;
    const int e0 = blockIdx.x * 32;
    const int wn   = t >> 6;
    const int lane = t & 63;
    const int g = lane >> 4, q = lane & 15;

    if (t < 32) {
        int ge = e0 + t;
        rs_s[t] = (ge < E) ? eidx[ge] : 0;
    }

    const int e_own  = t >> 3;
    const int chunk  = t & 7;
    const int ge_own = e0 + e_own;
    const int col_own = (ge_own < E) ? eidx[E + ge_own] : 0;
    uint4 yv[4];
    #pragma unroll
    for (int i = 0; i < 4; ++i)
        yv[i] = *reinterpret_cast<const uint4*>(y + (size_t)col_own * 256 + (i * 8 + chunk) * 8);

    {
        float d = (ge_own < E) ? dist[ge_own] : F_CUTOFF;
        float env = (d < F_CUTOFF) ? 0.5f * (__cosf(d * (F_PI / F_CUTOFF)) + 1.0f) : 0.0f;
        unsigned char* rowp = bufA + e_own * 512;
        int k0 = chunk * 8;
        #pragma unroll
        for (int i = 0; i < 4; ++i) {
            int n = k0 + 2 * i;
            float c0 = centers[n],     w0 = fabsf(widths[n]) + F_EPS_W;
            float c1 = centers[n + 1], w1 = fabsf(widths[n + 1]) + F_EPS_W;
            float z0 = (d - c0) / w0, z1 = (d - c1) / w1;
            float r0 = env * __expf(-0.5f * z0 * z0);
            float r1 = env * __expf(-0.5f * z1 * z1);
            unsigned u = (unsigned)f2bf(r0) | ((unsigned)f2bf(r1) << 16);
            int byte = (((n >> 3) ^ (e_own & 7)) << 4) + ((n & 7) * 2);
            *reinterpret_cast<unsigned*>(rowp + byte) = u;
        }
    }
    __syncthreads();

    mlp_stage<2, 1, true>(bufA, bufB, wt_rbf1, rbf_b1, wn, g, q);
    __syncthreads();
    mlp_stage<2, 4, true>(bufB, bufA, wt_comb, b_comb, wn, g, q);
    __syncthreads();
    mlp_stage<8, 4, true>(bufA, bufB, wt_f2, filt_b2, wn, g, q);
    __syncthreads();

    #pragma unroll
    for (int i = 0; i < 4; ++i)
        *reinterpret_cast<uint4*>(bufA + e_own * 512 + (i * 8 + chunk) * 16) = yv[i];
    __syncthreads();

    {
        f32x4 acc[2][4];
        #pragma unroll
        for (int mt = 0; mt < 2; ++mt)
            #pragma unroll
            for (int nt = 0; nt < 4; ++nt) acc[mt][nt] = (f32x4){0.f, 0.f, 0.f, 0.f};

        #pragma unroll
        for (int kk = 0; kk < 8; ++kk) {
            bf16x8 b[4];
            #pragma unroll
            for (int nt = 0; nt < 4; ++nt) {
                int n = (wn * 4 + nt) * 16 + q;
                b[nt] = *reinterpret_cast<const bf16x8*>(wt_f3 + n * 256 + kk * 32 + g * 8);
            }
            bf16x8 a[2];
            #pragma unroll
            for (int mt = 0; mt < 2; ++mt) {
                int m = mt * 16 + q;
                int unit = (4 * kk + g) ^ (m & 7);
                a[mt] = *reinterpret_cast<const bf16x8*>(bufB + m * 512 + unit * 16);
            }
            #pragma unroll
            for (int mt = 0; mt < 2; ++mt)
                #pragma unroll
                for (int nt = 0; nt < 4; ++nt)
                    acc[mt][nt] = __builtin_amdgcn_mfma_f32_16x16x32_bf16(a[mt], b[nt], acc[mt][nt], 0, 0, 0);
        }

        float bn[4];
        int   nn[4];
        #pragma unroll
        for (int nt = 0; nt < 4; ++nt) { nn[nt] = (wn * 4 + nt) * 16 + q; bn[nt] = filt_b3[nn[nt]]; }

        #pragma unroll
        for (int mt = 0; mt < 2; ++mt) {
            #pragma unroll
            for (int r = 0; r < 4; ++r) {
                int m  = mt * 16 + 4 * g + r;
                int ge = e0 + m;
                if (ge < E) {
                    const unsigned char* yrow = bufA + m * 512;
                    float* arow = agg + (size_t)rs_s[m] * 256;
                    #pragma unroll
                    for (int nt = 0; nt < 4; ++nt) {
                        float wv = acc[mt][nt][r] + bn[nt];
                        float yvv = bf2f(*reinterpret_cast<const ushort_t*>(yrow + nn[nt] * 2));
                        unsafeAtomicAdd(&arow[nn[nt]], wv * yvv);
                    }
                }
            }
        }
    }
}

__global__ __launch_bounds__(256)
void ln_kernel(const float* __restrict__ x, const float* __restrict__ agg,
               const float* __restrict__ g, const float* __restrict__ b,
               float* __restrict__ out0, int N)
{
    int lane = threadIdx.x & 63;
    int row  = blockIdx.x * 4 + (threadIdx.x >> 6);
    if (row >= N) return;
    float4 hx = reinterpret_cast<const float4*>(x)[row * 64 + lane];
    float4 ha = reinterpret_cast<const float4*>(agg)[row * 64 + lane];
    float4 h  = make_float4(hx.x + ha.x, hx.y + ha.y, hx.z + ha.z, hx.w + ha.w);
    float s  = h.x + h.y + h.z + h.w;
    float s2 = h.x * h.x + h.y * h.y + h.z * h.z + h.w * h.w;
    #pragma unroll
    for (int off = 32; off > 0; off >>= 1) {
        s  += __shfl_xor(s,  off, 64);
        s2 += __shfl_xor(s2, off, 64);
    }
    float mu  = s * (1.0f / 256.0f);
    float var = s2 * (1.0f / 256.0f) - mu * mu;
    float inv = rsqrtf(var + F_EPS_LN);
    float4 gv = reinterpret_cast<const float4*>(g)[lane];
    float4 bv = reinterpret_cast<const float4*>(b)[lane];
    float4 o;
    o.x = (h.x - mu) * inv * gv.x + bv.x;
    o.y = (h.y - mu) * inv * gv.y + bv.y;
    o.z = (h.z - mu) * inv * gv.z + bv.z;
    o.w = (h.w - mu) * inv * gv.w + bv.w;
    reinterpret_cast<float4*>(out0)[row * 64 + lane] = o;
}

// ---------------------------------------------------------------------------
extern "C" void kernel_launch(void* const* d_in, const int* in_sizes, int n_in,
                              void* d_out, int out_size, void* d_ws, size_t ws_size,
                              hipStream_t stream)
{
    const float* x       = (const float*)d_in[0];
    const int*   eidx    = (const int*)  d_in[1];
    const float* dist    = (const float*)d_in[2];
    const float* centers = (const float*)d_in[3];
    const float* widths  = (const float*)d_in[4];
    const float* rbf_w1  = (const float*)d_in[5];
    const float* rbf_b1  = (const float*)d_in[6];
    const float* rbf_w2  = (const float*)d_in[7];
    const float* rbf_b2  = (const float*)d_in[8];
    const float* filt_w1 = (const float*)d_in[9];
    const float* filt_b1 = (const float*)d_in[10];
    const float* filt_w2 = (const float*)d_in[11];
    const float* filt_b2 = (const float*)d_in[12];
    const float* filt_w3 = (const float*)d_in[13];
    const float* filt_b3 = (const float*)d_in[14];
    const float* node_w  = (const float*)d_in[15];
    const float* node_b  = (const float*)d_in[16];
    const float* ln_g    = (const float*)d_in[17];
    const float* ln_b    = (const float*)d_in[18];
    const float* gate_w  = (const float*)d_in[19];
    const float* gate_b  = (const float*)d_in[20];

    const int N = in_sizes[0] / 256;
    const int E = in_sizes[2];

    char* wsb = (char*)d_ws;
    size_t off = 0;
    auto alloc = [&](size_t bytes, size_t align) -> char* {
        off = (off + align - 1) & ~(align - 1);
        char* p = wsb + off;
        off += bytes;
        return p;
    };
    ushort_t* y_bf  = (ushort_t*)alloc((size_t)N * 256 * 2, 16);
    ushort_t* wt1   = (ushort_t*)alloc(64 * 64 * 2, 16);
    ushort_t* wcomb = (ushort_t*)alloc(256 * 64 * 2, 16);
    ushort_t* wf2t  = (ushort_t*)alloc(256 * 256 * 2, 16);
    ushort_t* wf3t  = (ushort_t*)alloc(256 * 256 * 2, 16);
    float*    bcomb = (float*)   alloc(256 * 4, 16);
    int*      cnt   = (int*)     alloc((size_t)N * 4, 16);      // becomes cursor
    int*      start = (int*)     alloc(((size_t)N + 1) * 4, 16);
    int*      colp  = (int*)     alloc((size_t)E * 4, 16);
    int*      nodep = (int*)     alloc((size_t)E * 4, 16);
    float*    distp = (float*)   alloc((size_t)E * 4, 16);
    const bool csr_fits = (off <= ws_size);

    dim3 b256(256);

    // weight prep
    cvt_transpose_kernel<<<dim3((64 * 64 + 255) / 256),   b256, 0, stream>>>(rbf_w1,  wt1, 64, 64, 6);
    combine_w_kernel<<<dim3(64), b256, 0, stream>>>(rbf_w2, filt_w1, wcomb);
    combine_b_kernel<<<dim3(1), b256, 0, stream>>>(rbf_b2, filt_w1, filt_b1, bcomb);
    cvt_transpose_kernel<<<dim3((256 * 256 + 255) / 256), b256, 0, stream>>>(filt_w2, wf2t, 256, 256, 8);
    cvt_transpose_kernel<<<dim3((256 * 256 + 255) / 256), b256, 0, stream>>>(filt_w3, wf3t, 256, 256, 8);

    gemm256_bf16_kernel<<<dim3((N + 63) / 64), b256, 0, stream>>>(x, node_w, node_b, y_bf, N);

    hipMemsetAsync(d_out, 0, (size_t)out_size * sizeof(float), stream);

    if (csr_fits) {
        hipMemsetAsync(cnt, 0, (size_t)N * 4, stream);
        count_kernel<<<dim3((E + 255) / 256), b256, 0, stream>>>(eidx, cnt, E);
        scan_kernel<<<dim3(1), 1024, 0, stream>>>(cnt, start, N);
        scatter_kernel<<<dim3((E + 255) / 256), b256, 0, stream>>>(eidx, dist, cnt, colp, nodep, distp, E);

        edge_csr_kernel<<<dim3((E + 31) / 32), b256, 0, stream>>>(
            distp, colp, nodep, start, centers, widths,
            wt1, rbf_b1, wcomb, bcomb,
            wf2t, filt_b2, wf3t, filt_b3,
            y_bf, (float*)d_out, E);
    } else {
        edge_atomic_kernel<<<dim3((E + 31) / 32), b256, 0, stream>>>(
            dist, eidx, centers, widths,
            wt1, rbf_b1, wcomb, bcomb,
            wf2t, filt_b2, wf3t, filt_b3,
            y_bf, (float*)d_out, E);
    }

    ln_kernel<<<dim3((N + 3) / 4), b256, 0, stream>>>(x, (float*)d_out, ln_g, ln_b, (float*)d_out, N);
    gate_gemm_kernel<<<dim3((N + 63) / 64), b256, 0, stream>>>((float*)d_out, gate_w, gate_b, (float*)d_out, N);
}